// Round 2
// baseline (327.168 us; speedup 1.0000x reference)
//
#include <hip/hip_runtime.h>
#include <hip/hip_bf16.h>

#define B_   32
#define L_   2048
#define CIN  256
#define HID  512
#define TL   64
#define NLT  (L_ / TL)   // 32 l-tiles per batch

typedef __bf16 bf16_t;
typedef __bf16 bf16x8 __attribute__((ext_vector_type(8)));
typedef __bf16 bf16x4 __attribute__((ext_vector_type(4)));
typedef float  f32x4  __attribute__((ext_vector_type(4)));

__device__ __forceinline__ float fast_tanh(float v) {
    float x = fminf(fmaxf(v, -9.0f), 9.0f);
    float e = exp2f(x * 2.885390081777927f);           // e^{2x}
    return (e - 1.0f) * __builtin_amdgcn_rcpf(e + 1.0f);
}

// ---------------------------------------------------------------------------
// Kernel 1: cast weights fp32 -> bf16 into workspace
// ---------------------------------------------------------------------------
__global__ void cast_weights_kernel(const float* __restrict__ W1, const float* __restrict__ W2,
                                    bf16_t* __restrict__ W1b, bf16_t* __restrict__ W2b)
{
    int i = blockIdx.x * blockDim.x + threadIdx.x;
    if (i < HID * CIN) W1b[i] = (bf16_t)W1[i];
    if (i < HID * HID) W2b[i] = (bf16_t)W2[i];
}

// ---------------------------------------------------------------------------
// Kernel 2: fused project(x), project(y), tanh*tanh, partial row-reduction.
// Block = (batch b, 64-row L-tile). 512 threads = 8 waves; wave w owns
// output cols [w*64, w*64+64). MFMA 16x16x32 bf16.
// A-tile (32 KB) and H-tile (64 KB) ALIAS one 64 KB LDS buffer -> 2 blocks/CU.
// ---------------------------------------------------------------------------
__global__ __launch_bounds__(512, 4)
void fused_proj_kernel(const float* __restrict__ x, const float* __restrict__ y,
                       const bf16_t* __restrict__ W1b, const float* __restrict__ b1,
                       const bf16_t* __restrict__ W2b, const float* __restrict__ b2,
                       float* __restrict__ partial)
{
    __shared__ char U[TL * HID * 2];     // 64 KB: A-tile aliases H-tile

    const int tid  = threadIdx.x;
    const int lane = tid & 63;
    const int wv   = tid >> 6;           // wave 0..7
    const int l15  = lane & 15;
    const int l4   = lane >> 4;
    const int blk  = blockIdx.x;
    const int b    = blk >> 5;           // batch
    const int lt   = blk & 31;           // l-tile
    const int col0 = wv * 64;            // this wave's output-col base

    const float* xrows = x + ((size_t)(b * L_) + (size_t)lt * TL) * CIN;
    const float* yrows = y + ((size_t)(b * L_) + (size_t)lt * TL) * CIN;

    float bias1[4], bias2[4];
#pragma unroll
    for (int j = 0; j < 4; ++j) {
        bias1[j] = b1[col0 + j * 16 + l15];
        bias2[j] = b2[col0 + j * 16 + l15];
    }

    // --- stage a [TL x CIN] fp32 tile -> bf16 into A region (XOR-swizzled)
    auto stage = [&](const float* src) {
        const int r = tid >> 3;          // 64 rows, 8 threads per row
        const int q = tid & 7;
        const float4* srow = reinterpret_cast<const float4*>(src + (size_t)r * CIN);
        char* rowp = U + r * (CIN * 2);
        const unsigned swz = (unsigned)((r & 15) << 4);
#pragma unroll
        for (int c = 0; c < 8; ++c) {
            const int f = q + 8 * c;     // float4 index within row (coalesced)
            float4 v = srow[f];
            bf16x4 h;
            h[0] = (bf16_t)v.x; h[1] = (bf16_t)v.y; h[2] = (bf16_t)v.z; h[3] = (bf16_t)v.w;
            *reinterpret_cast<bf16x4*>(rowp + (((unsigned)(8 * f)) ^ swz)) = h;
        }
    };

    // --- GEMM1: [TL x CIN](LDS A) x W1b[HID x CIN] -> acc
    auto gemm1 = [&](f32x4 (&acc)[4][4]) {
#pragma unroll
        for (int i = 0; i < 4; ++i)
#pragma unroll
            for (int j = 0; j < 4; ++j) acc[i][j] = (f32x4){0.f, 0.f, 0.f, 0.f};
        for (int kk = 0; kk < CIN / 32; ++kk) {
            bf16x8 a[4], w[4];
#pragma unroll
            for (int i = 0; i < 4; ++i) {
                int r = i * 16 + l15;
                unsigned off = (unsigned)(r * (CIN * 2)) +
                               (((unsigned)(kk * 64 + l4 * 16)) ^ ((unsigned)((r & 15) << 4)));
                a[i] = *reinterpret_cast<const bf16x8*>(U + off);
            }
#pragma unroll
            for (int j = 0; j < 4; ++j) {
                int cc = col0 + j * 16 + l15;
                w[j] = *reinterpret_cast<const bf16x8*>(W1b + (size_t)cc * CIN + kk * 32 + l4 * 8);
            }
#pragma unroll
            for (int i = 0; i < 4; ++i)
#pragma unroll
                for (int j = 0; j < 4; ++j)
                    acc[i][j] = __builtin_amdgcn_mfma_f32_16x16x32_bf16(a[i], w[j], acc[i][j], 0, 0, 0);
        }
    };

    // --- write H1 = acc + b1 as bf16 into H region (XOR-swizzled)
    auto writeH = [&](f32x4 (&acc)[4][4]) {
#pragma unroll
        for (int i = 0; i < 4; ++i)
#pragma unroll
            for (int j = 0; j < 4; ++j) {
                unsigned colb = (unsigned)((col0 + j * 16 + l15) * 2);
#pragma unroll
                for (int r2 = 0; r2 < 4; ++r2) {
                    int r = i * 16 + l4 * 4 + r2;
                    float v = acc[i][j][r2] + bias1[j];
                    *reinterpret_cast<bf16_t*>(U + r * (HID * 2) +
                                               (colb ^ ((unsigned)((r & 15) << 4)))) = (bf16_t)v;
                }
            }
    };

    // --- GEMM2: [TL x HID](LDS H) x W2b[HID x HID] -> acc
    auto gemm2 = [&](f32x4 (&acc)[4][4]) {
#pragma unroll
        for (int i = 0; i < 4; ++i)
#pragma unroll
            for (int j = 0; j < 4; ++j) acc[i][j] = (f32x4){0.f, 0.f, 0.f, 0.f};
        for (int kk = 0; kk < HID / 32; ++kk) {
            bf16x8 a[4], w[4];
#pragma unroll
            for (int i = 0; i < 4; ++i) {
                int r = i * 16 + l15;
                unsigned off = (unsigned)(r * (HID * 2)) +
                               (((unsigned)(kk * 64 + l4 * 16)) ^ ((unsigned)((r & 15) << 4)));
                a[i] = *reinterpret_cast<const bf16x8*>(U + off);
            }
#pragma unroll
            for (int j = 0; j < 4; ++j) {
                int cc = col0 + j * 16 + l15;
                w[j] = *reinterpret_cast<const bf16x8*>(W2b + (size_t)cc * HID + kk * 32 + l4 * 8);
            }
#pragma unroll
            for (int i = 0; i < 4; ++i)
#pragma unroll
                for (int j = 0; j < 4; ++j)
                    acc[i][j] = __builtin_amdgcn_mfma_f32_16x16x32_bf16(a[i], w[j], acc[i][j], 0, 0, 0);
        }
    };

    f32x4 acc[4][4];
    f32x4 tx[4][4];

    // ---- x pipeline
    stage(xrows);
    __syncthreads();                 // A(x) ready
    gemm1(acc);
    __syncthreads();                 // all A(x) reads done (H will clobber A)
    writeH(acc);
    __syncthreads();                 // H(x) ready
    gemm2(acc);
#pragma unroll
    for (int i = 0; i < 4; ++i)
#pragma unroll
        for (int j = 0; j < 4; ++j)
#pragma unroll
            for (int r2 = 0; r2 < 4; ++r2)
                tx[i][j][r2] = fast_tanh(acc[i][j][r2] + bias2[j]);
    __syncthreads();                 // all H(x) reads done (y stage will clobber)

    // ---- y pipeline
    stage(yrows);
    __syncthreads();                 // A(y) ready
    gemm1(acc);
    __syncthreads();                 // all A(y) reads done
    writeH(acc);
    __syncthreads();                 // H(y) ready
    gemm2(acc);

    // ---- product + reduce over the tile's 64 rows
    float colsum[4] = {0.f, 0.f, 0.f, 0.f};
#pragma unroll
    for (int i = 0; i < 4; ++i)
#pragma unroll
        for (int j = 0; j < 4; ++j)
#pragma unroll
            for (int r2 = 0; r2 < 4; ++r2) {
                float ty = fast_tanh(acc[i][j][r2] + bias2[j]);
                colsum[j] += tx[i][j][r2] * ty;
            }
#pragma unroll
    for (int j = 0; j < 4; ++j) {
        colsum[j] += __shfl_xor(colsum[j], 16);
        colsum[j] += __shfl_xor(colsum[j], 32);
    }
    if (lane < 16) {
#pragma unroll
        for (int j = 0; j < 4; ++j)
            partial[(size_t)blk * HID + col0 + j * 16 + lane] = colsum[j];
    }
}

// ---------------------------------------------------------------------------
// Kernel 3: sum the 32 l-tile partials per batch -> out[B][HID]
// ---------------------------------------------------------------------------
__global__ void reduce_kernel(const float* __restrict__ partial, float* __restrict__ out)
{
    int b = blockIdx.x;
    int g = threadIdx.x;             // 512 threads
    float s = 0.f;
#pragma unroll
    for (int t = 0; t < NLT; ++t)
        s += partial[((size_t)(b * NLT + t)) * HID + g];
    out[b * HID + g] = s;
}

extern "C" void kernel_launch(void* const* d_in, const int* in_sizes, int n_in,
                              void* d_out, int out_size, void* d_ws, size_t ws_size,
                              hipStream_t stream)
{
    const float* x  = (const float*)d_in[0];
    const float* y  = (const float*)d_in[1];
    const float* W1 = (const float*)d_in[2];
    const float* b1 = (const float*)d_in[3];
    const float* W2 = (const float*)d_in[4];
    const float* b2 = (const float*)d_in[5];
    float* out = (float*)d_out;

    char* ws = (char*)d_ws;
    bf16_t* W1b    = (bf16_t*)ws;                    // 256 KB
    bf16_t* W2b    = (bf16_t*)(ws + (256 << 10));    // 512 KB
    float*  partial = (float*)(ws + (768 << 10));    // 2 MB (1024 blocks x 512)

    hipLaunchKernelGGL(cast_weights_kernel, dim3(1024), dim3(256), 0, stream, W1, W2, W1b, W2b);
    hipLaunchKernelGGL(fused_proj_kernel, dim3(B_ * NLT), dim3(512), 0, stream,
                       x, y, W1b, b1, W2b, b2, partial);
    hipLaunchKernelGGL(reduce_kernel, dim3(B_), dim3(512), 0, stream, partial, out);
}

// Round 3
// 257.919 us; speedup vs baseline: 1.2685x; 1.2685x over previous
//
#include <hip/hip_runtime.h>
#include <hip/hip_bf16.h>

#define B_   32
#define L_   2048
#define CIN  256
#define HID  512
#define TL   64
#define NLT  (L_ / TL)   // 32 l-tiles per batch

typedef __bf16 bf16_t;
typedef __bf16 bf16x8 __attribute__((ext_vector_type(8)));
typedef __bf16 bf16x4 __attribute__((ext_vector_type(4)));
typedef float  f32x4  __attribute__((ext_vector_type(4)));

__device__ __forceinline__ float fast_tanh(float v) {
    float x = fminf(fmaxf(v, -9.0f), 9.0f);
    float e = exp2f(x * 2.885390081777927f);           // e^{2x}
    return (e - 1.0f) * __builtin_amdgcn_rcpf(e + 1.0f);
}

// ---------------------------------------------------------------------------
// Kernel 1: cast weights fp32 -> bf16 into workspace
// ---------------------------------------------------------------------------
__global__ void cast_weights_kernel(const float* __restrict__ W1, const float* __restrict__ W2,
                                    bf16_t* __restrict__ W1b, bf16_t* __restrict__ W2b)
{
    int i = blockIdx.x * blockDim.x + threadIdx.x;
    if (i < HID * CIN) W1b[i] = (bf16_t)W1[i];
    if (i < HID * HID) W2b[i] = (bf16_t)W2[i];
}

// ---------------------------------------------------------------------------
// Kernel 2: fused project(x), project(y), tanh*tanh, partial row-reduction.
// Block = (batch b, 64-row L-tile). 512 threads = 8 waves; wave w owns
// output cols [w*64, w*64+64). MFMA 16x16x32 bf16.
// A-tile (32 KB) and H-tile (64 KB) ALIAS one 64 KB LDS buffer -> 2 blocks/CU.
// launch_bounds min-waves/EU = 2 -> 256-VGPR cap (128 used; NO spill —
// (512,4) forced a 64-VGPR cap and 380 MB of scratch traffic in round 2).
// ---------------------------------------------------------------------------
__global__ __launch_bounds__(512, 2)
void fused_proj_kernel(const float* __restrict__ x, const float* __restrict__ y,
                       const bf16_t* __restrict__ W1b, const float* __restrict__ b1,
                       const bf16_t* __restrict__ W2b, const float* __restrict__ b2,
                       float* __restrict__ partial)
{
    __shared__ char U[TL * HID * 2];     // 64 KB: A-tile aliases H-tile

    const int tid  = threadIdx.x;
    const int lane = tid & 63;
    const int wv   = tid >> 6;           // wave 0..7
    const int l15  = lane & 15;
    const int l4   = lane >> 4;
    const int blk  = blockIdx.x;
    const int b    = blk >> 5;           // batch
    const int lt   = blk & 31;           // l-tile
    const int col0 = wv * 64;            // this wave's output-col base

    const float* xrows = x + ((size_t)(b * L_) + (size_t)lt * TL) * CIN;
    const float* yrows = y + ((size_t)(b * L_) + (size_t)lt * TL) * CIN;

    float bias1[4], bias2[4];
#pragma unroll
    for (int j = 0; j < 4; ++j) {
        bias1[j] = b1[col0 + j * 16 + l15];
        bias2[j] = b2[col0 + j * 16 + l15];
    }

    // --- stage a [TL x CIN] fp32 tile -> bf16 into A region (XOR-swizzled)
    auto stage = [&](const float* src) {
        const int r = tid >> 3;          // 64 rows, 8 threads per row
        const int q = tid & 7;
        const float4* srow = reinterpret_cast<const float4*>(src + (size_t)r * CIN);
        char* rowp = U + r * (CIN * 2);
        const unsigned swz = (unsigned)((r & 15) << 4);
#pragma unroll
        for (int c = 0; c < 8; ++c) {
            const int f = q + 8 * c;     // float4 index within row (coalesced)
            float4 v = srow[f];
            bf16x4 h;
            h[0] = (bf16_t)v.x; h[1] = (bf16_t)v.y; h[2] = (bf16_t)v.z; h[3] = (bf16_t)v.w;
            *reinterpret_cast<bf16x4*>(rowp + (((unsigned)(8 * f)) ^ swz)) = h;
        }
    };

    // --- GEMM1: [TL x CIN](LDS A) x W1b[HID x CIN] -> acc
    auto gemm1 = [&](f32x4 (&acc)[4][4]) {
#pragma unroll
        for (int i = 0; i < 4; ++i)
#pragma unroll
            for (int j = 0; j < 4; ++j) acc[i][j] = (f32x4){0.f, 0.f, 0.f, 0.f};
        for (int kk = 0; kk < CIN / 32; ++kk) {
            bf16x8 a[4], w[4];
#pragma unroll
            for (int i = 0; i < 4; ++i) {
                int r = i * 16 + l15;
                unsigned off = (unsigned)(r * (CIN * 2)) +
                               (((unsigned)(kk * 64 + l4 * 16)) ^ ((unsigned)((r & 15) << 4)));
                a[i] = *reinterpret_cast<const bf16x8*>(U + off);
            }
#pragma unroll
            for (int j = 0; j < 4; ++j) {
                int cc = col0 + j * 16 + l15;
                w[j] = *reinterpret_cast<const bf16x8*>(W1b + (size_t)cc * CIN + kk * 32 + l4 * 8);
            }
#pragma unroll
            for (int i = 0; i < 4; ++i)
#pragma unroll
                for (int j = 0; j < 4; ++j)
                    acc[i][j] = __builtin_amdgcn_mfma_f32_16x16x32_bf16(a[i], w[j], acc[i][j], 0, 0, 0);
        }
    };

    // --- write H1 = acc + b1 as bf16 into H region (XOR-swizzled)
    auto writeH = [&](f32x4 (&acc)[4][4]) {
#pragma unroll
        for (int i = 0; i < 4; ++i)
#pragma unroll
            for (int j = 0; j < 4; ++j) {
                unsigned colb = (unsigned)((col0 + j * 16 + l15) * 2);
#pragma unroll
                for (int r2 = 0; r2 < 4; ++r2) {
                    int r = i * 16 + l4 * 4 + r2;
                    float v = acc[i][j][r2] + bias1[j];
                    *reinterpret_cast<bf16_t*>(U + r * (HID * 2) +
                                               (colb ^ ((unsigned)((r & 15) << 4)))) = (bf16_t)v;
                }
            }
    };

    // --- GEMM2: [TL x HID](LDS H) x W2b[HID x HID] -> acc
    auto gemm2 = [&](f32x4 (&acc)[4][4]) {
#pragma unroll
        for (int i = 0; i < 4; ++i)
#pragma unroll
            for (int j = 0; j < 4; ++j) acc[i][j] = (f32x4){0.f, 0.f, 0.f, 0.f};
        for (int kk = 0; kk < HID / 32; ++kk) {
            bf16x8 a[4], w[4];
#pragma unroll
            for (int i = 0; i < 4; ++i) {
                int r = i * 16 + l15;
                unsigned off = (unsigned)(r * (HID * 2)) +
                               (((unsigned)(kk * 64 + l4 * 16)) ^ ((unsigned)((r & 15) << 4)));
                a[i] = *reinterpret_cast<const bf16x8*>(U + off);
            }
#pragma unroll
            for (int j = 0; j < 4; ++j) {
                int cc = col0 + j * 16 + l15;
                w[j] = *reinterpret_cast<const bf16x8*>(W2b + (size_t)cc * HID + kk * 32 + l4 * 8);
            }
#pragma unroll
            for (int i = 0; i < 4; ++i)
#pragma unroll
                for (int j = 0; j < 4; ++j)
                    acc[i][j] = __builtin_amdgcn_mfma_f32_16x16x32_bf16(a[i], w[j], acc[i][j], 0, 0, 0);
        }
    };

    f32x4 acc[4][4];
    bf16x4 tx[4][4];                 // tanh(x-proj) held as bf16 (saves 32 VGPRs)

    // ---- x pipeline
    stage(xrows);
    __syncthreads();                 // A(x) ready
    gemm1(acc);
    __syncthreads();                 // all A(x) reads done (H will clobber A)
    writeH(acc);
    __syncthreads();                 // H(x) ready
    gemm2(acc);
#pragma unroll
    for (int i = 0; i < 4; ++i)
#pragma unroll
        for (int j = 0; j < 4; ++j)
#pragma unroll
            for (int r2 = 0; r2 < 4; ++r2)
                tx[i][j][r2] = (bf16_t)fast_tanh(acc[i][j][r2] + bias2[j]);
    __syncthreads();                 // all H(x) reads done (y stage will clobber)

    // ---- y pipeline
    stage(yrows);
    __syncthreads();                 // A(y) ready
    gemm1(acc);
    __syncthreads();                 // all A(y) reads done
    writeH(acc);
    __syncthreads();                 // H(y) ready
    gemm2(acc);

    // ---- product + reduce over the tile's 64 rows
    float colsum[4] = {0.f, 0.f, 0.f, 0.f};
#pragma unroll
    for (int i = 0; i < 4; ++i)
#pragma unroll
        for (int j = 0; j < 4; ++j)
#pragma unroll
            for (int r2 = 0; r2 < 4; ++r2) {
                float ty = fast_tanh(acc[i][j][r2] + bias2[j]);
                colsum[j] += (float)tx[i][j][r2] * ty;
            }
#pragma unroll
    for (int j = 0; j < 4; ++j) {
        colsum[j] += __shfl_xor(colsum[j], 16);
        colsum[j] += __shfl_xor(colsum[j], 32);
    }
    if (lane < 16) {
#pragma unroll
        for (int j = 0; j < 4; ++j)
            partial[(size_t)blk * HID + col0 + j * 16 + lane] = colsum[j];
    }
}

// ---------------------------------------------------------------------------
// Kernel 3: sum the 32 l-tile partials per batch -> out[B][HID]
// ---------------------------------------------------------------------------
__global__ void reduce_kernel(const float* __restrict__ partial, float* __restrict__ out)
{
    int b = blockIdx.x;
    int g = threadIdx.x;             // 512 threads
    float s = 0.f;
#pragma unroll
    for (int t = 0; t < NLT; ++t)
        s += partial[((size_t)(b * NLT + t)) * HID + g];
    out[b * HID + g] = s;
}

extern "C" void kernel_launch(void* const* d_in, const int* in_sizes, int n_in,
                              void* d_out, int out_size, void* d_ws, size_t ws_size,
                              hipStream_t stream)
{
    const float* x  = (const float*)d_in[0];
    const float* y  = (const float*)d_in[1];
    const float* W1 = (const float*)d_in[2];
    const float* b1 = (const float*)d_in[3];
    const float* W2 = (const float*)d_in[4];
    const float* b2 = (const float*)d_in[5];
    float* out = (float*)d_out;

    char* ws = (char*)d_ws;
    bf16_t* W1b    = (bf16_t*)ws;                    // 256 KB
    bf16_t* W2b    = (bf16_t*)(ws + (256 << 10));    // 512 KB
    float*  partial = (float*)(ws + (768 << 10));    // 2 MB (1024 blocks x 512)

    hipLaunchKernelGGL(cast_weights_kernel, dim3(1024), dim3(256), 0, stream, W1, W2, W1b, W2b);
    hipLaunchKernelGGL(fused_proj_kernel, dim3(B_ * NLT), dim3(512), 0, stream,
                       x, y, W1b, b1, W2b, b2, partial);
    hipLaunchKernelGGL(reduce_kernel, dim3(B_), dim3(512), 0, stream, partial, out);
}

// Round 4
// 149.615 us; speedup vs baseline: 2.1867x; 1.7239x over previous
//
#include <hip/hip_runtime.h>
#include <hip/hip_bf16.h>

#define B_   32
#define L_   2048
#define CIN  256
#define HID  512
#define TL   64
#define NLT  (L_ / TL)   // 32 l-tiles per batch

typedef __bf16 bf16_t;
typedef __bf16 bf16x8 __attribute__((ext_vector_type(8)));
typedef __bf16 bf16x4 __attribute__((ext_vector_type(4)));
typedef float  f32x4  __attribute__((ext_vector_type(4)));

#define AX_OFF 0u
#define AY_OFF 65536u
#define HX_OFF 0u
#define HY_OFF 65536u

__device__ __forceinline__ float fast_tanh(float v) {
    float x = fminf(fmaxf(v, -9.0f), 9.0f);
    float e = exp2f(x * 2.885390081777927f);           // e^{2x}
    return (e - 1.0f) * __builtin_amdgcn_rcpf(e + 1.0f);
}

// ---------------------------------------------------------------------------
// Kernel 1: cast weights fp32 -> bf16 into workspace
// ---------------------------------------------------------------------------
__global__ void cast_weights_kernel(const float* __restrict__ W1, const float* __restrict__ W2,
                                    bf16_t* __restrict__ W1b, bf16_t* __restrict__ W2b)
{
    int i = blockIdx.x * blockDim.x + threadIdx.x;
    if (i < HID * CIN) W1b[i] = (bf16_t)W1[i];
    if (i < HID * HID) W2b[i] = (bf16_t)W2[i];
}

// ---------------------------------------------------------------------------
// Kernel 2: fused project(x)+project(y) simultaneously, tanh*tanh, partial
// row-reduction. Block = 1024 threads (16 waves) on one (batch, 64-row tile).
// Wave w owns output cols [w*32, w*32+32) and accumulates BOTH x and y
// pipelines sharing each weight fragment (halves weight traffic, kills the
// tx[] array). LDS 128 KB: A(x)/A(y) alias into H(x)/H(y). 3 barriers.
// 1024-thread block needs 4 waves/SIMD -> compiler must fit <=128 total regs.
// ---------------------------------------------------------------------------
__global__ __launch_bounds__(1024, 4)
void fused_proj_kernel(const float* __restrict__ x, const float* __restrict__ y,
                       const bf16_t* __restrict__ W1b, const float* __restrict__ b1,
                       const bf16_t* __restrict__ W2b, const float* __restrict__ b2,
                       float* __restrict__ partial)
{
    __shared__ char U[131072];           // 128 KB

    const int tid  = threadIdx.x;
    const int lane = tid & 63;
    const int wv   = tid >> 6;           // wave 0..15
    const int l15  = lane & 15;
    const int l4   = lane >> 4;
    const int blk  = blockIdx.x;
    const int b    = blk >> 5;           // batch
    const int lt   = blk & 31;           // l-tile
    const int col0 = wv * 32;            // this wave's output-col base

    const float* xrows = x + ((size_t)(b * L_) + (size_t)lt * TL) * CIN;
    const float* yrows = y + ((size_t)(b * L_) + (size_t)lt * TL) * CIN;

    float bias1[2], bias2[2];
#pragma unroll
    for (int j = 0; j < 2; ++j) {
        bias1[j] = b1[col0 + j * 16 + l15];
        bias2[j] = b2[col0 + j * 16 + l15];
    }

    // --- stage: waves 0-7 stage x -> A(x), waves 8-15 stage y -> A(y).
    {
        const int t = tid & 511;
        const float* src = (tid < 512) ? xrows : yrows;
        const unsigned base = (tid < 512) ? AX_OFF : AY_OFF;
        const int r = t >> 3;            // 64 rows, 8 threads/row
        const int q = t & 7;
        const float4* srow = reinterpret_cast<const float4*>(src + (size_t)r * CIN);
        char* rowp = U + base + r * (CIN * 2);
        const unsigned swz = (unsigned)((r & 15) << 4);
#pragma unroll
        for (int c = 0; c < 8; ++c) {
            const int f = q + 8 * c;     // float4 index within row (coalesced)
            float4 v = srow[f];
            bf16x4 h;
            h[0] = (bf16_t)v.x; h[1] = (bf16_t)v.y; h[2] = (bf16_t)v.z; h[3] = (bf16_t)v.w;
            *reinterpret_cast<bf16x4*>(rowp + (((unsigned)(8 * f)) ^ swz)) = h;
        }
    }
    __syncthreads();                     // A(x), A(y) ready

    f32x4 accx[4][2], accy[4][2];
#pragma unroll
    for (int i = 0; i < 4; ++i)
#pragma unroll
        for (int j = 0; j < 2; ++j) {
            accx[i][j] = (f32x4){0.f, 0.f, 0.f, 0.f};
            accy[i][j] = (f32x4){0.f, 0.f, 0.f, 0.f};
        }

    // --- GEMM1 (x and y share the W1 stream)
    for (int kk = 0; kk < CIN / 32; ++kk) {
        bf16x8 w[2];
#pragma unroll
        for (int j = 0; j < 2; ++j) {
            int cc = col0 + j * 16 + l15;
            w[j] = *reinterpret_cast<const bf16x8*>(W1b + (size_t)cc * CIN + kk * 32 + l4 * 8);
        }
#pragma unroll
        for (int i = 0; i < 4; ++i) {
            int r = i * 16 + l15;
            unsigned off = (unsigned)(r * (CIN * 2)) +
                           (((unsigned)(kk * 64 + l4 * 16)) ^ ((unsigned)((r & 15) << 4)));
            bf16x8 ax = *reinterpret_cast<const bf16x8*>(U + AX_OFF + off);
            bf16x8 ay = *reinterpret_cast<const bf16x8*>(U + AY_OFF + off);
#pragma unroll
            for (int j = 0; j < 2; ++j) {
                accx[i][j] = __builtin_amdgcn_mfma_f32_16x16x32_bf16(ax, w[j], accx[i][j], 0, 0, 0);
                accy[i][j] = __builtin_amdgcn_mfma_f32_16x16x32_bf16(ay, w[j], accy[i][j], 0, 0, 0);
            }
        }
    }
    __syncthreads();                     // all A reads done (H clobbers A)

    // --- write H1 = acc + b1 (bf16, swizzled) for both pipelines
#pragma unroll
    for (int i = 0; i < 4; ++i)
#pragma unroll
        for (int j = 0; j < 2; ++j) {
            unsigned colb = (unsigned)((col0 + j * 16 + l15) * 2);
#pragma unroll
            for (int r2 = 0; r2 < 4; ++r2) {
                int r = i * 16 + l4 * 4 + r2;
                unsigned off = (unsigned)(r * (HID * 2)) + (colb ^ ((unsigned)((r & 15) << 4)));
                *reinterpret_cast<bf16_t*>(U + HX_OFF + off) = (bf16_t)(accx[i][j][r2] + bias1[j]);
                *reinterpret_cast<bf16_t*>(U + HY_OFF + off) = (bf16_t)(accy[i][j][r2] + bias1[j]);
            }
        }
    __syncthreads();                     // H(x), H(y) ready

#pragma unroll
    for (int i = 0; i < 4; ++i)
#pragma unroll
        for (int j = 0; j < 2; ++j) {
            accx[i][j] = (f32x4){0.f, 0.f, 0.f, 0.f};
            accy[i][j] = (f32x4){0.f, 0.f, 0.f, 0.f};
        }

    // --- GEMM2 (x and y share the W2 stream)
    for (int kk = 0; kk < HID / 32; ++kk) {
        bf16x8 w[2];
#pragma unroll
        for (int j = 0; j < 2; ++j) {
            int cc = col0 + j * 16 + l15;
            w[j] = *reinterpret_cast<const bf16x8*>(W2b + (size_t)cc * HID + kk * 32 + l4 * 8);
        }
#pragma unroll
        for (int i = 0; i < 4; ++i) {
            int r = i * 16 + l15;
            unsigned off = (unsigned)(r * (HID * 2)) +
                           (((unsigned)(kk * 64 + l4 * 16)) ^ ((unsigned)((r & 15) << 4)));
            bf16x8 ax = *reinterpret_cast<const bf16x8*>(U + HX_OFF + off);
            bf16x8 ay = *reinterpret_cast<const bf16x8*>(U + HY_OFF + off);
#pragma unroll
            for (int j = 0; j < 2; ++j) {
                accx[i][j] = __builtin_amdgcn_mfma_f32_16x16x32_bf16(ax, w[j], accx[i][j], 0, 0, 0);
                accy[i][j] = __builtin_amdgcn_mfma_f32_16x16x32_bf16(ay, w[j], accy[i][j], 0, 0, 0);
            }
        }
    }

    // --- product + reduce over the tile's 64 rows (no LDS needed)
    float colsum[2] = {0.f, 0.f};
#pragma unroll
    for (int i = 0; i < 4; ++i)
#pragma unroll
        for (int j = 0; j < 2; ++j)
#pragma unroll
            for (int r2 = 0; r2 < 4; ++r2) {
                float tx = fast_tanh(accx[i][j][r2] + bias2[j]);
                float ty = fast_tanh(accy[i][j][r2] + bias2[j]);
                colsum[j] += tx * ty;
            }
#pragma unroll
    for (int j = 0; j < 2; ++j) {
        colsum[j] += __shfl_xor(colsum[j], 16);
        colsum[j] += __shfl_xor(colsum[j], 32);
    }
    if (lane < 16) {
#pragma unroll
        for (int j = 0; j < 2; ++j)
            partial[(size_t)blk * HID + col0 + j * 16 + lane] = colsum[j];
    }
}

// ---------------------------------------------------------------------------
// Kernel 3: sum the 32 l-tile partials per batch -> out[B][HID]
// ---------------------------------------------------------------------------
__global__ void reduce_kernel(const float* __restrict__ partial, float* __restrict__ out)
{
    int b = blockIdx.x;
    int g = threadIdx.x;             // 512 threads
    float s = 0.f;
#pragma unroll
    for (int t = 0; t < NLT; ++t)
        s += partial[((size_t)(b * NLT + t)) * HID + g];
    out[b * HID + g] = s;
}

extern "C" void kernel_launch(void* const* d_in, const int* in_sizes, int n_in,
                              void* d_out, int out_size, void* d_ws, size_t ws_size,
                              hipStream_t stream)
{
    const float* x  = (const float*)d_in[0];
    const float* y  = (const float*)d_in[1];
    const float* W1 = (const float*)d_in[2];
    const float* b1 = (const float*)d_in[3];
    const float* W2 = (const float*)d_in[4];
    const float* b2 = (const float*)d_in[5];
    float* out = (float*)d_out;

    char* ws = (char*)d_ws;
    bf16_t* W1b    = (bf16_t*)ws;                    // 256 KB
    bf16_t* W2b    = (bf16_t*)(ws + (256 << 10));    // 512 KB
    float*  partial = (float*)(ws + (768 << 10));    // 2 MB (1024 blocks x 512)

    hipLaunchKernelGGL(cast_weights_kernel, dim3(1024), dim3(256), 0, stream, W1, W2, W1b, W2b);
    hipLaunchKernelGGL(fused_proj_kernel, dim3(B_ * NLT), dim3(1024), 0, stream,
                       x, y, W1b, b1, W2b, b2, partial);
    hipLaunchKernelGGL(reduce_kernel, dim3(B_), dim3(512), 0, stream, partial, out);
}